// Round 2
// baseline (473.992 us; speedup 1.0000x reference)
//
#include <hip/hip_runtime.h>
#include <hip/hip_cooperative_groups.h>
#include <math.h>

namespace cg = cooperative_groups;

#define NUM_HEADS   16
#define HEAD_DIM    64
#define KMAXN       64
#define LOCAL_WIN   512
#define LOG_N       17
#define LEAF_START  131072
#define MAX_LEN_TOK 65536
#define ROW         1024      // NUM_HEADS*HEAD_DIM floats per token
#define SLICE       65536     // 64 tokens * ROW floats per partial slice
#define MAXN        34

typedef float vf4 __attribute__((ext_vector_type(4)));

__device__ __forceinline__ vf4 ntload(const float* p) {
    return __builtin_nontemporal_load((const vf4*)p);
}

// ============================ cooperative mega-kernel ========================
// Phase 1: K1 chunk-sum partial units (big nodes, K=64 always) + 16 local-
//          attention units running CONCURRENTLY (no K1 dependency).
// grid.sync()
// Phase 2: 96 (node,head) tiles: reduce CB partial slices for own head slice
//          into LDS, then node attention (round-0-verified 4-wave numerics).
// grid.sync()
// Phase 3: combine out = local + mean(node_out).
struct MArgs {
    int nBig, nNodes, pos, bbK1, nUnits, nTiles;
    int offNodeOut, offLocalOut;
    // big-node (K1) arrays
    int a1[MAXN], cpb[MAXN], C1[MAXN], off1[MAXN], bbase[MAXN];
    // all-node (phase 2) arrays
    int K2n[MAXN], C2[MAXN], CB2[MAXN], off2[MAXN], a2[MAXN], dep[MAXN];
};

__global__ __launch_bounds__(256, 4) void mega(const float* __restrict__ v,
                                               const float* __restrict__ q,
                                               const float* __restrict__ W,
                                               const float* __restrict__ temp,
                                               float* __restrict__ out,
                                               float* __restrict__ ws,
                                               MArgs A) {
    int tid  = threadIdx.x;
    int lane = tid & 63;
    int w    = tid >> 6;                   // wave 0..3
    float* node_out  = ws + A.offNodeOut;
    float* local_out = ws + A.offLocalOut;

    __shared__ float fh[64][64];           // phase-2 f head slice [k][d]
    __shared__ float qs[64], qds[64], sv[64], ps[64];
    __shared__ float red[4][64];
    __shared__ float sc[LOCAL_WIN];
    __shared__ float wred[8];
    __shared__ float mS[2];

    // ---------------- phase 1 ----------------
    for (int u = blockIdx.x; u < A.nUnits; u += gridDim.x) {
        if (u < A.bbK1) {
            // K1 unit: big nodes only -> K=64, kgc=16, cb-major decode
            int node = 0;
            for (int i = 1; i < A.nBig; ++i) if (u >= A.bbase[i]) node = i;
            int lb = u - A.bbase[node];
            int cb = lb >> 4;
            int kg = lb & 15;
            int k0 = kg << 2;
            int c0 = cb * A.cpb[node];
            int c1 = c0 + A.cpb[node];
            if (c1 > A.C1[node]) c1 = A.C1[node];
            int j4 = tid * 4;

            vf4 acc0 = 0.f, acc1 = 0.f, acc2 = 0.f, acc3 = 0.f;
            int c = c0;
            for (; c + 2 <= c1; c += 2) {
                const float* p0 = v + (long)(A.a1[node] + c * 64 + k0) * ROW + j4;
                const float* p1 = p0 + SLICE;
                vf4 y0 = ntload(p0);
                vf4 y1 = ntload(p0 + ROW);
                vf4 y2 = ntload(p0 + 2 * ROW);
                vf4 y3 = ntload(p0 + 3 * ROW);
                vf4 z0 = ntload(p1);
                vf4 z1 = ntload(p1 + ROW);
                vf4 z2 = ntload(p1 + 2 * ROW);
                vf4 z3 = ntload(p1 + 3 * ROW);
                acc0 += y0 + z0; acc1 += y1 + z1; acc2 += y2 + z2; acc3 += y3 + z3;
            }
            if (c < c1) {
                const float* p0 = v + (long)(A.a1[node] + c * 64 + k0) * ROW + j4;
                acc0 += ntload(p0);
                acc1 += ntload(p0 + ROW);
                acc2 += ntload(p0 + 2 * ROW);
                acc3 += ntload(p0 + 3 * ROW);
            }
            float* wp = ws + (long)A.off1[node] + (long)cb * SLICE + (long)k0 * ROW + j4;
            *(vf4*)(wp)           = acc0;
            *(vf4*)(wp + ROW)     = acc1;
            *(vf4*)(wp + 2 * ROW) = acc2;
            *(vf4*)(wp + 3 * ROW) = acc3;
        } else {
            // local-window attention for head h, 256 threads (2 tokens/thread)
            int h    = u - A.bbK1;
            int nloc = A.pos < LOCAL_WIN ? A.pos : LOCAL_WIN;
            int t0   = A.pos - nloc;

            if (tid < 64) qs[tid] = q[h * 64 + tid];
            __syncthreads();

            float s0 = -1e30f, s1 = -1e30f;
            if (tid < nloc) {
                const float* vr = v + (long)(t0 + tid) * ROW + h * 64;
                float acc = 0.f;
                #pragma unroll 8
                for (int d = 0; d < 64; ++d) acc += qs[d] * vr[d];
                s0 = acc * 0.125f;
            }
            if (tid + 256 < nloc) {
                const float* vr = v + (long)(t0 + tid + 256) * ROW + h * 64;
                float acc = 0.f;
                #pragma unroll 8
                for (int d = 0; d < 64; ++d) acc += qs[d] * vr[d];
                s1 = acc * 0.125f;
            }
            float mx = fmaxf(s0, s1);
            #pragma unroll
            for (int m = 1; m < 64; m <<= 1) mx = fmaxf(mx, __shfl_xor(mx, m, 64));
            if (lane == 0) wred[w] = mx;
            __syncthreads();
            if (tid == 0) {
                float m2 = wred[0];
                for (int i = 1; i < 4; ++i) m2 = fmaxf(m2, wred[i]);
                mS[0] = m2;
            }
            __syncthreads();
            float m = mS[0];

            float e0 = (tid < nloc)       ? expf(s0 - m) : 0.f;
            float e1 = (tid + 256 < nloc) ? expf(s1 - m) : 0.f;
            sc[tid]       = e0;
            sc[tid + 256] = e1;
            float su = e0 + e1;
            #pragma unroll
            for (int mm = 1; mm < 64; mm <<= 1) su += __shfl_xor(su, mm, 64);
            if (lane == 0) wred[4 + w] = su;
            __syncthreads();
            if (tid == 0) {
                float S2 = 0.f;
                for (int i = 0; i < 4; ++i) S2 += wred[4 + i];
                mS[1] = S2;
            }
            __syncthreads();
            float S = mS[1];

            // lane = d; wave w handles tokens [w*128, w*128+128)
            float acc = 0.f;
            {
                const float* vb = v + (long)t0 * ROW + h * 64 + lane;
                int tb = w * 128;
                #pragma unroll 4
                for (int i = 0; i < 128; ++i) {
                    int t = tb + i;
                    if (t < nloc) acc += sc[t] * vb[(long)t * ROW];
                }
            }
            red[w][lane] = acc;
            __syncthreads();
            if (w == 0) {
                float tot = red[0][lane] + red[1][lane] + red[2][lane] + red[3][lane];
                local_out[h * 64 + lane] = (nloc > 0) ? tot / S : 0.f;
            }
            __syncthreads();
        }
    }

    cg::this_grid().sync();

    // ---------------- phase 2: node attention tiles ----------------
    for (int t = blockIdx.x; t < A.nTiles; t += gridDim.x) {
        int node = t >> 4;
        int h    = t & 15;
        int K    = A.K2n[node];

        if (tid < 64) qs[tid] = q[h * 64 + tid];

        const float* bp; int CB; float invC;
        if (A.C2[node] > 1) {
            bp   = ws + (long)A.off2[node] + h * 64;
            CB   = A.CB2[node];
            invC = 1.0f / (float)A.C2[node];
        } else {
            bp   = v + (long)A.a2[node] * ROW + h * 64;   // read chunk directly
            CB   = 1;
            invC = 1.0f;
        }
        // 64 rows x 16 float4-cols = 1024 items; 4 per thread
        for (int id = tid; id < 1024; id += 256) {
            int r  = id >> 4;
            int c4 = (id & 15) << 2;
            if (r < K) {
                vf4 s0 = 0.f, s1 = 0.f, s2 = 0.f, s3 = 0.f;
                const float* p = bp + (long)r * ROW + c4;
                int cb = 0;
                for (; cb + 4 <= CB; cb += 4) {
                    s0 += *(const vf4*)(p + (long)cb * SLICE);
                    s1 += *(const vf4*)(p + (long)(cb + 1) * SLICE);
                    s2 += *(const vf4*)(p + (long)(cb + 2) * SLICE);
                    s3 += *(const vf4*)(p + (long)(cb + 3) * SLICE);
                }
                for (; cb < CB; ++cb) s0 += *(const vf4*)(p + (long)cb * SLICE);
                s0 += s1; s2 += s3; s0 += s2;
                s0 *= invC;
                *(vf4*)&fh[r][c4] = s0;
            }
        }
        __syncthreads();

        int dep = A.dep[node];
        float qp = 0.f;
        const float* Wr = W + ((long)dep * 64 + lane) * 64;
        #pragma unroll
        for (int e = w * 16; e < w * 16 + 16; ++e) qp += qs[e] * Wr[e];
        red[w][lane] = qp;
        __syncthreads();
        if (w == 0) qds[lane] = qs[lane] + red[0][lane] + red[1][lane] + red[2][lane] + red[3][lane];
        __syncthreads();
        float qd    = qds[lane];
        float sp    = log1pf(expf(temp[dep]));
        float scale = 1.0f / ((sp + 1e-6f) * 8.0f);

        for (int k = w; k < K; k += 4) {
            float p2 = qd * fh[k][lane];
            #pragma unroll
            for (int m = 1; m < 64; m <<= 1) p2 += __shfl_xor(p2, m, 64);
            if (lane == 0) sv[k] = p2 * scale;
        }
        __syncthreads();

        if (w == 0) {
            float s  = (lane < K) ? sv[lane] : -1e30f;
            float mx = s;
            #pragma unroll
            for (int m = 1; m < 64; m <<= 1) mx = fmaxf(mx, __shfl_xor(mx, m, 64));
            float e = (lane < K) ? expf(s - mx) : 0.f;
            float S = e;
            #pragma unroll
            for (int m = 1; m < 64; m <<= 1) S += __shfl_xor(S, m, 64);
            ps[lane] = e / S;
        }
        __syncthreads();

        float o = 0.f;
        for (int k = w; k < K; k += 4) o += ps[k] * fh[k][lane];
        red[w][lane] = o;
        __syncthreads();
        if (w == 0)
            node_out[(long)node * ROW + h * 64 + lane] =
                red[0][lane] + red[1][lane] + red[2][lane] + red[3][lane];
        __syncthreads();
    }

    cg::this_grid().sync();

    // ---------------- phase 3: combine ----------------
    if (blockIdx.x < 4) {
        int i = blockIdx.x * 256 + tid;   // 0..1023 = h*64+d
        float tr = 0.f;
        for (int n = 0; n < A.nNodes; ++n) tr += node_out[(long)n * ROW + i];
        if (A.nNodes > 0) tr /= (float)A.nNodes;
        out[i] = local_out[i] + tr;
    }
}

// ============================ legacy fallback (round-1 verified) =============
struct K1Args {
    int nNodes;
    int a[MAXN]; int cpb[MAXN]; int C[MAXN]; int CB[MAXN]; int K[MAXN];
    int off[MAXN]; int bbase[MAXN];
};
struct K2Args {
    int nNodes;
    int K[MAXN]; int C[MAXN]; int CB[MAXN]; int off[MAXN]; int a[MAXN]; int depth[MAXN];
};

__global__ __launch_bounds__(256, 4) void k1_reduce(const float* __restrict__ v,
                                                    float* __restrict__ ws,
                                                    K1Args A) {
    int b = blockIdx.x;
    int node = 0;
    for (int i = 1; i < A.nNodes; ++i)
        if (b >= A.bbase[i]) node = i;
    int lb  = b - A.bbase[node];
    int K   = A.K[node];
    int kgc = (K + 3) >> 2;
    int cb  = lb / kgc;
    int kg  = lb - cb * kgc;
    int k0  = kg * 4;
    int RK  = K - k0; if (RK > 4) RK = 4;
    int c0  = cb * A.cpb[node];
    int c1  = c0 + A.cpb[node];
    int C   = A.C[node];
    if (c1 > C) c1 = C;
    int j4 = threadIdx.x * 4;
    vf4 acc0 = 0.f, acc1 = 0.f, acc2 = 0.f, acc3 = 0.f;
    if (RK == 4) {
        int c = c0;
        for (; c + 2 <= c1; c += 2) {
            const float* p0 = v + (long)(A.a[node] + c * 64 + k0) * ROW + j4;
            const float* p1 = p0 + SLICE;
            vf4 y0 = ntload(p0); vf4 y1 = ntload(p0 + ROW);
            vf4 y2 = ntload(p0 + 2 * ROW); vf4 y3 = ntload(p0 + 3 * ROW);
            vf4 z0 = ntload(p1); vf4 z1 = ntload(p1 + ROW);
            vf4 z2 = ntload(p1 + 2 * ROW); vf4 z3 = ntload(p1 + 3 * ROW);
            acc0 += y0 + z0; acc1 += y1 + z1; acc2 += y2 + z2; acc3 += y3 + z3;
        }
        if (c < c1) {
            const float* p0 = v + (long)(A.a[node] + c * 64 + k0) * ROW + j4;
            acc0 += ntload(p0); acc1 += ntload(p0 + ROW);
            acc2 += ntload(p0 + 2 * ROW); acc3 += ntload(p0 + 3 * ROW);
        }
    } else {
        for (int c = c0; c < c1; ++c) {
            const float* p0 = v + (long)(A.a[node] + c * 64 + k0) * ROW + j4;
            if (RK > 0) acc0 += ntload(p0);
            if (RK > 1) acc1 += ntload(p0 + ROW);
            if (RK > 2) acc2 += ntload(p0 + 2 * ROW);
            if (RK > 3) acc3 += ntload(p0 + 3 * ROW);
        }
    }
    float* wp = ws + (long)A.off[node] + (long)cb * SLICE + (long)k0 * ROW + j4;
    if (RK > 0) *(vf4*)(wp)           = acc0;
    if (RK > 1) *(vf4*)(wp + ROW)     = acc1;
    if (RK > 2) *(vf4*)(wp + 2 * ROW) = acc2;
    if (RK > 3) *(vf4*)(wp + 3 * ROW) = acc3;
}

__global__ __launch_bounds__(512) void k2_fused(const float* __restrict__ v,
                                                const float* __restrict__ ws,
                                                const float* __restrict__ q,
                                                const float* __restrict__ W,
                                                const float* __restrict__ temp,
                                                float* __restrict__ node_out,
                                                float* __restrict__ local_out,
                                                int pos, K2Args A) {
    int h    = blockIdx.x;
    int node = blockIdx.y;
    int tid  = threadIdx.x;
    int lane = tid & 63;
    int w    = tid >> 6;

    __shared__ float fh[64][64];
    __shared__ float qs[64], qds[64], sv[64], ps[64];
    __shared__ float red[8][64];
    __shared__ float sc[LOCAL_WIN];
    __shared__ float wred[16];
    __shared__ float mS[2];

    if (node < A.nNodes) {
        int K = A.K[node];
        if (tid < 64) qs[tid] = q[h * 64 + tid];
        const float* bp; int CB; float invC;
        if (A.C[node] > 1) {
            bp = ws + (long)A.off[node] + h * 64; CB = A.CB[node];
            invC = 1.0f / (float)A.C[node];
        } else {
            bp = v + (long)A.a[node] * ROW + h * 64; CB = 1; invC = 1.0f;
        }
        for (int id = tid; id < 1024; id += 512) {
            int r = id >> 4; int c4 = (id & 15) << 2;
            if (r < K) {
                vf4 s0 = 0.f, s1 = 0.f, s2 = 0.f, s3 = 0.f;
                const float* p = bp + (long)r * ROW + c4;
                int cb = 0;
                for (; cb + 4 <= CB; cb += 4) {
                    s0 += *(const vf4*)(p + (long)cb * SLICE);
                    s1 += *(const vf4*)(p + (long)(cb + 1) * SLICE);
                    s2 += *(const vf4*)(p + (long)(cb + 2) * SLICE);
                    s3 += *(const vf4*)(p + (long)(cb + 3) * SLICE);
                }
                for (; cb < CB; ++cb) s0 += *(const vf4*)(p + (long)cb * SLICE);
                s0 += s1; s2 += s3; s0 += s2; s0 *= invC;
                *(vf4*)&fh[r][c4] = s0;
            }
        }
        __syncthreads();
        int dep = A.depth[node];
        float qp = 0.f;
        const float* Wr = W + ((long)dep * 64 + lane) * 64;
        #pragma unroll
        for (int e = w * 8; e < w * 8 + 8; ++e) qp += qs[e] * Wr[e];
        red[w][lane] = qp;
        __syncthreads();
        if (w == 0) {
            float t2 = qs[lane];
            #pragma unroll
            for (int i = 0; i < 8; ++i) t2 += red[i][lane];
            qds[lane] = t2;
        }
        __syncthreads();
        float qd = qds[lane];
        float sp = log1pf(expf(temp[dep]));
        float scale = 1.0f / ((sp + 1e-6f) * 8.0f);
        for (int k = w; k < K; k += 8) {
            float p = qd * fh[k][lane];
            #pragma unroll
            for (int m = 1; m < 64; m <<= 1) p += __shfl_xor(p, m, 64);
            if (lane == 0) sv[k] = p * scale;
        }
        __syncthreads();
        if (w == 0) {
            float s = (lane < K) ? sv[lane] : -1e30f;
            float mx = s;
            #pragma unroll
            for (int m = 1; m < 64; m <<= 1) mx = fmaxf(mx, __shfl_xor(mx, m, 64));
            float e = (lane < K) ? expf(s - mx) : 0.f;
            float S = e;
            #pragma unroll
            for (int m = 1; m < 64; m <<= 1) S += __shfl_xor(S, m, 64);
            ps[lane] = e / S;
        }
        __syncthreads();
        float o = 0.f;
        for (int k = w; k < K; k += 8) o += ps[k] * fh[k][lane];
        red[w][lane] = o;
        __syncthreads();
        if (w == 0) {
            float t2 = 0.f;
            #pragma unroll
            for (int i = 0; i < 8; ++i) t2 += red[i][lane];
            node_out[node * ROW + h * 64 + lane] = t2;
        }
    } else {
        int nloc = pos < LOCAL_WIN ? pos : LOCAL_WIN;
        int t0 = pos - nloc;
        if (tid < 64) qs[tid] = q[h * 64 + tid];
        __syncthreads();
        float s = -1e30f;
        if (tid < nloc) {
            const float* vr = v + (long)(t0 + tid) * ROW + h * 64;
            float acc = 0.f;
            #pragma unroll 8
            for (int d = 0; d < 64; ++d) acc += qs[d] * vr[d];
            s = acc * 0.125f;
        }
        float mx = s;
        #pragma unroll
        for (int m = 1; m < 64; m <<= 1) mx = fmaxf(mx, __shfl_xor(mx, m, 64));
        if (lane == 0) wred[w] = mx;
        __syncthreads();
        if (tid == 0) {
            float m2 = wred[0];
            for (int i = 1; i < 8; ++i) m2 = fmaxf(m2, wred[i]);
            mS[0] = m2;
        }
        __syncthreads();
        float m = mS[0];
        float e = (tid < nloc) ? expf(s - m) : 0.f;
        sc[tid] = e;
        float su = e;
        #pragma unroll
        for (int mm = 1; mm < 64; mm <<= 1) su += __shfl_xor(su, mm, 64);
        if (lane == 0) wred[8 + w] = su;
        __syncthreads();
        if (tid == 0) {
            float S2 = 0.f;
            for (int i = 0; i < 8; ++i) S2 += wred[8 + i];
            mS[1] = S2;
        }
        __syncthreads();
        float S = mS[1];
        float acc = 0.f;
        {
            const float* vb = v + (long)t0 * ROW + h * 64 + lane;
            int tb = w * 64;
            #pragma unroll 4
            for (int i = 0; i < 64; ++i) {
                int t = tb + i;
                if (t < nloc) acc += sc[t] * vb[(long)t * ROW];
            }
        }
        red[w][lane] = acc;
        __syncthreads();
        if (w == 0) {
            float tot = 0.f;
            #pragma unroll
            for (int i = 0; i < 8; ++i) tot += red[i][lane];
            local_out[h * 64 + lane] = (nloc > 0) ? tot / S : 0.f;
        }
    }
}

__global__ __launch_bounds__(256) void k3_combine(const float* __restrict__ node_out,
                                                  const float* __restrict__ local_out,
                                                  int nNodes,
                                                  float* __restrict__ out) {
    int i = blockIdx.x * 256 + threadIdx.x;
    float tr = 0.f;
    for (int n = 0; n < nNodes; ++n) tr += node_out[(long)n * ROW + i];
    if (nNodes > 0) tr /= (float)nNodes;
    out[i] = local_out[i] + tr;
}

static int floor_log2_host(unsigned x) { int r = 0; while (x >>= 1) ++r; return r; }

extern "C" void kernel_launch(void* const* d_in, const int* in_sizes, int n_in,
                              void* d_out, int out_size, void* d_ws, size_t ws_size,
                              hipStream_t stream) {
    const float* v    = (const float*)d_in[0];
    const float* q    = (const float*)d_in[1];
    const float* W    = (const float*)d_in[2];
    const float* temp = (const float*)d_in[3];
    float* out        = (float*)d_out;
    float* ws         = (float*)d_ws;

    int pos = in_sizes[0] / ROW;

    int n_nodes = 0;
    int nv[MAXN], nd[MAXN];
    if (pos > 0) {
        long l = LEAF_START;
        long r = LEAF_START + (pos < MAX_LEN_TOK ? pos : MAX_LEN_TOK);
        while (l < r) {
            if (l & 1) { nv[n_nodes] = (int)l; nd[n_nodes] = LOG_N - floor_log2_host((unsigned)l); ++n_nodes; ++l; }
            if (r & 1) { --r; nv[n_nodes] = (int)r; nd[n_nodes] = LOG_N - floor_log2_host((unsigned)r); ++n_nodes; }
            l >>= 1; r >>= 1;
        }
    }

    // cpb: smallest in {32,...} whose partial slices fit ws.
    // ws layout: partials | node_out [n_nodes*ROW] | local_out [ROW]
    int cpb_choice = 1024;
    for (int cand : {32, 64, 128, 256, 512, 1024}) {
        long tot_cb = 0;
        for (int i = 0; i < n_nodes; ++i) {
            int L = 1 << nd[i];
            int C = (L > KMAXN) ? L / KMAXN : 1;
            if (C > 1) tot_cb += (C + cand - 1) / cand;
        }
        long need = (tot_cb * (long)SLICE + (long)n_nodes * ROW + ROW) * 4;
        if (need <= (long)ws_size) { cpb_choice = cand; break; }
    }

    MArgs A{}; K1Args A1{}; K2Args A2{};
    A.nNodes = n_nodes; A.pos = pos;
    A2.nNodes = n_nodes;
    int off = 0, bb = 0, nBig = 0;
    for (int i = 0; i < n_nodes; ++i) {
        int depth = nd[i];
        int L = 1 << depth;
        int a = (nv[i] << depth) - LEAF_START;
        int K = (L < KMAXN) ? L : KMAXN;
        int C = (L > KMAXN) ? L / KMAXN : 1;
        A.K2n[i] = K; A.C2[i] = C; A.a2[i] = a; A.dep[i] = depth;
        A2.K[i] = K; A2.C[i] = C; A2.a[i] = a; A2.depth[i] = depth;
        if (C > 1) {
            int CB  = (C + cpb_choice - 1) / cpb_choice;
            int cpb = (C + CB - 1) / CB;
            A.a1[nBig] = a; A.cpb[nBig] = cpb; A.C1[nBig] = C;
            A.off1[nBig] = off; A.bbase[nBig] = bb;
            A1.a[nBig] = a; A1.cpb[nBig] = cpb; A1.C[nBig] = C;
            A1.CB[nBig] = CB; A1.K[nBig] = K; A1.off[nBig] = off; A1.bbase[nBig] = bb;
            A.CB2[i] = CB; A.off2[i] = off;
            A2.CB[i] = CB; A2.off[i] = off;
            off += CB * SLICE;
            bb  += 16 * CB;            // K=64 -> 16 k-groups per cb
            ++nBig;
        } else {
            A.CB2[i] = 1; A.off2[i] = 0;
            A2.CB[i] = 1; A2.off[i] = 0;
        }
    }
    A.nBig = nBig; A1.nNodes = nBig;
    A.bbK1 = bb;
    A.nUnits = bb + NUM_HEADS;
    A.nTiles = n_nodes * NUM_HEADS;
    A.offNodeOut  = off;
    A.offLocalOut = off + n_nodes * ROW;

    float* node_outp  = ws + (long)A.offNodeOut;
    float* local_outp = ws + (long)A.offLocalOut;

    // grid size: co-residency-safe via occupancy query (cached)
    static int s_grid = 0;
    if (s_grid == 0) {
        int dev = 0;
        hipGetDevice(&dev);
        int perCU = 0;
        if (hipOccupancyMaxActiveBlocksPerMultiprocessor(&perCU,
                reinterpret_cast<const void*>(mega), 256, 0) != hipSuccess || perCU < 1)
            perCU = 2;
        int nCU = 0;
        if (hipDeviceGetAttribute(&nCU, hipDeviceAttributeMultiprocessorCount, dev)
                != hipSuccess || nCU < 1)
            nCU = 256;
        long g = (long)perCU * nCU;
        if (g > 1024) g = 1024;
        if (g < 64)   g = 64;
        s_grid = (int)g;
    }

    void* kp[] = { (void*)&v, (void*)&q, (void*)&W, (void*)&temp,
                   (void*)&out, (void*)&ws, (void*)&A };
    hipError_t err = hipLaunchCooperativeKernel(
        reinterpret_cast<const void*>(mega), dim3(s_grid), dim3(256), kp, 0, stream);

    if (err != hipSuccess) {
        // fallback: round-1 verified 3-kernel path
        if (nBig > 0)
            hipLaunchKernelGGL(k1_reduce, dim3(bb), dim3(256), 0, stream, v, ws, A1);
        hipLaunchKernelGGL(k2_fused, dim3(NUM_HEADS, n_nodes + 1), dim3(512), 0, stream,
                           v, ws, q, W, temp, node_outp, local_outp, pos, A2);
        hipLaunchKernelGGL(k3_combine, dim3(4), dim3(256), 0, stream,
                           node_outp, local_outp, n_nodes, out);
    }
}

// Round 3
// 302.022 us; speedup vs baseline: 1.5694x; 1.5694x over previous
//
#include <hip/hip_runtime.h>
#include <math.h>

#define NUM_HEADS   16
#define HEAD_DIM    64
#define KMAXN       64
#define LOCAL_WIN   512
#define LOG_N       17
#define LEAF_START  131072
#define MAX_LEN_TOK 65536
#define ROW         1024      // NUM_HEADS*HEAD_DIM floats per token
#define SLICE       65536     // 64 tokens * ROW floats per partial slice
#define MAXN        34

typedef float vf4 __attribute__((ext_vector_type(4)));

__device__ __forceinline__ vf4 ntload(const float* p) {
    return __builtin_nontemporal_load((const vf4*)p);
}

// ---------------------------------------------------------------------------
// Shared per-(node,head) attention tile: reduce CB strided slices (stride
// SLICE floats) into LDS f-slice, then 4-wave attention. Verified numerics
// (round-0/round-2 mega, absmax 0.0).
// ---------------------------------------------------------------------------
__device__ __forceinline__ void attn_tile(const float* __restrict__ bp, int CB, float invC,
                                          int K, int dep, int h,
                                          const float* __restrict__ q,
                                          const float* __restrict__ W,
                                          const float* __restrict__ temp,
                                          float* __restrict__ node_out_row,
                                          float (&fh)[64][64], float* qs, float* qds,
                                          float* sv, float* ps, float (&red)[4][64]) {
    int tid = threadIdx.x, lane = tid & 63, w = tid >> 6;
    if (tid < 64) qs[tid] = q[h * 64 + tid];
    // 64 rows x 16 float4-cols = 1024 items; 4 per thread
    for (int id = tid; id < 1024; id += 256) {
        int r = id >> 4, c4 = (id & 15) << 2;
        if (r < K) {
            vf4 s0 = 0.f, s1 = 0.f, s2 = 0.f, s3 = 0.f;
            const float* p = bp + (long)r * ROW + c4;
            int cb = 0;
            for (; cb + 4 <= CB; cb += 4) {
                s0 += *(const vf4*)(p + (long)cb * SLICE);
                s1 += *(const vf4*)(p + (long)(cb + 1) * SLICE);
                s2 += *(const vf4*)(p + (long)(cb + 2) * SLICE);
                s3 += *(const vf4*)(p + (long)(cb + 3) * SLICE);
            }
            for (; cb < CB; ++cb) s0 += *(const vf4*)(p + (long)cb * SLICE);
            s0 += s1; s2 += s3; s0 += s2;
            s0 *= invC;
            *(vf4*)&fh[r][c4] = s0;
        }
    }
    __syncthreads();

    // q_depth = q + q @ W[dep]^T
    float qp = 0.f;
    const float* Wr = W + ((long)dep * 64 + lane) * 64;
    #pragma unroll
    for (int e = w * 16; e < w * 16 + 16; ++e) qp += qs[e] * Wr[e];
    red[w][lane] = qp;
    __syncthreads();
    if (w == 0) qds[lane] = qs[lane] + red[0][lane] + red[1][lane] + red[2][lane] + red[3][lane];
    __syncthreads();
    float qd    = qds[lane];
    float sp    = log1pf(expf(temp[dep]));
    float scale = 1.0f / ((sp + 1e-6f) * 8.0f);

    for (int k = w; k < K; k += 4) {
        float p2 = qd * fh[k][lane];
        #pragma unroll
        for (int m = 1; m < 64; m <<= 1) p2 += __shfl_xor(p2, m, 64);
        if (lane == 0) sv[k] = p2 * scale;
    }
    __syncthreads();

    if (w == 0) {
        float s  = (lane < K) ? sv[lane] : -1e30f;
        float mx = s;
        #pragma unroll
        for (int m = 1; m < 64; m <<= 1) mx = fmaxf(mx, __shfl_xor(mx, m, 64));
        float e = (lane < K) ? expf(s - mx) : 0.f;
        float S = e;
        #pragma unroll
        for (int m = 1; m < 64; m <<= 1) S += __shfl_xor(S, m, 64);
        ps[lane] = e / S;
    }
    __syncthreads();

    float o = 0.f;
    for (int k = w; k < K; k += 4) o += ps[k] * fh[k][lane];
    red[w][lane] = o;
    __syncthreads();
    if (w == 0)
        node_out_row[lane] = red[0][lane] + red[1][lane] + red[2][lane] + red[3][lane];
}

// ---------------------------------------------------------------------------
// KA: [0, bbK1)            -> K1 partial-sum units (C>8 nodes, K=64, cb-major)
//     [bbK1, bbK1+16)      -> local-window attention, one head per block
//     [bbK1+16, ...)       -> direct (C<=8) node tiles, straight from v
// Block 0 zeroes the KB completion counter (stream order makes it visible).
// ---------------------------------------------------------------------------
struct KAArgs {
    int nPart, bbK1, nDirect, pos;
    int offLocal, offCnt, offNodeOut;
    int a1[MAXN], cpb1[MAXN], C1[MAXN], off1[MAXN], bbase[MAXN];
    int aD[MAXN], CD[MAXN], KD[MAXN], depD[MAXN], idxD[MAXN];
};

__global__ __launch_bounds__(256, 4) void kA(const float* __restrict__ v,
                                             const float* __restrict__ q,
                                             const float* __restrict__ W,
                                             const float* __restrict__ temp,
                                             float* __restrict__ ws, KAArgs A) {
    __shared__ float fh[64][64];
    __shared__ float qs[64], qds[64], sv[64], ps[64];
    __shared__ float red[4][64];
    __shared__ float sc[LOCAL_WIN];
    __shared__ float wred[8];
    __shared__ float mS[2];

    int b = blockIdx.x, tid = threadIdx.x;
    int lane = tid & 63, w = tid >> 6;
    if (b == 0 && tid == 0) *((unsigned*)(ws + A.offCnt)) = 0u;

    if (b < A.bbK1) {
        // ---- K1 partial unit (round-1 verified inner loop; K=64 always) ----
        int node = 0;
        for (int i = 1; i < A.nPart; ++i) if (b >= A.bbase[i]) node = i;
        int lb = b - A.bbase[node];
        int cb = lb >> 4, kg = lb & 15, k0 = kg << 2;
        int c0 = cb * A.cpb1[node];
        int c1 = c0 + A.cpb1[node];
        if (c1 > A.C1[node]) c1 = A.C1[node];
        int j4 = tid * 4;

        vf4 acc0 = 0.f, acc1 = 0.f, acc2 = 0.f, acc3 = 0.f;
        int c = c0;
        for (; c + 2 <= c1; c += 2) {
            const float* p0 = v + (long)(A.a1[node] + c * 64 + k0) * ROW + j4;
            const float* p1 = p0 + SLICE;
            vf4 y0 = ntload(p0);
            vf4 y1 = ntload(p0 + ROW);
            vf4 y2 = ntload(p0 + 2 * ROW);
            vf4 y3 = ntload(p0 + 3 * ROW);
            vf4 z0 = ntload(p1);
            vf4 z1 = ntload(p1 + ROW);
            vf4 z2 = ntload(p1 + 2 * ROW);
            vf4 z3 = ntload(p1 + 3 * ROW);
            acc0 += y0 + z0; acc1 += y1 + z1; acc2 += y2 + z2; acc3 += y3 + z3;
        }
        if (c < c1) {
            const float* p0 = v + (long)(A.a1[node] + c * 64 + k0) * ROW + j4;
            acc0 += ntload(p0);
            acc1 += ntload(p0 + ROW);
            acc2 += ntload(p0 + 2 * ROW);
            acc3 += ntload(p0 + 3 * ROW);
        }
        float* wp = ws + (long)A.off1[node] + (long)cb * SLICE + (long)k0 * ROW + j4;
        *(vf4*)(wp)           = acc0;
        *(vf4*)(wp + ROW)     = acc1;
        *(vf4*)(wp + 2 * ROW) = acc2;
        *(vf4*)(wp + 3 * ROW) = acc3;
    } else if (b < A.bbK1 + NUM_HEADS) {
        // ---- local-window attention, head h, 2 tokens/thread (verified) ----
        int h    = b - A.bbK1;
        int nloc = A.pos < LOCAL_WIN ? A.pos : LOCAL_WIN;
        int t0   = A.pos - nloc;

        if (tid < 64) qs[tid] = q[h * 64 + tid];
        __syncthreads();

        float s0 = -1e30f, s1 = -1e30f;
        if (tid < nloc) {
            const float* vr = v + (long)(t0 + tid) * ROW + h * 64;
            float acc = 0.f;
            #pragma unroll 8
            for (int d = 0; d < 64; ++d) acc += qs[d] * vr[d];
            s0 = acc * 0.125f;
        }
        if (tid + 256 < nloc) {
            const float* vr = v + (long)(t0 + tid + 256) * ROW + h * 64;
            float acc = 0.f;
            #pragma unroll 8
            for (int d = 0; d < 64; ++d) acc += qs[d] * vr[d];
            s1 = acc * 0.125f;
        }
        float mx = fmaxf(s0, s1);
        #pragma unroll
        for (int m = 1; m < 64; m <<= 1) mx = fmaxf(mx, __shfl_xor(mx, m, 64));
        if (lane == 0) wred[w] = mx;
        __syncthreads();
        if (tid == 0) {
            float m2 = wred[0];
            for (int i = 1; i < 4; ++i) m2 = fmaxf(m2, wred[i]);
            mS[0] = m2;
        }
        __syncthreads();
        float m = mS[0];

        float e0 = (tid < nloc)       ? expf(s0 - m) : 0.f;
        float e1 = (tid + 256 < nloc) ? expf(s1 - m) : 0.f;
        sc[tid]       = e0;
        sc[tid + 256] = e1;
        float su = e0 + e1;
        #pragma unroll
        for (int mm = 1; mm < 64; mm <<= 1) su += __shfl_xor(su, mm, 64);
        if (lane == 0) wred[4 + w] = su;
        __syncthreads();
        if (tid == 0) {
            float S2 = 0.f;
            for (int i = 0; i < 4; ++i) S2 += wred[4 + i];
            mS[1] = S2;
        }
        __syncthreads();
        float S = mS[1];

        float acc = 0.f;
        {
            const float* vb = v + (long)t0 * ROW + h * 64 + lane;
            int tb = w * 128;
            #pragma unroll 4
            for (int i = 0; i < 128; ++i) {
                int t = tb + i;
                if (t < nloc) acc += sc[t] * vb[(long)t * ROW];
            }
        }
        red[w][lane] = acc;
        __syncthreads();
        if (w == 0) {
            float tot = red[0][lane] + red[1][lane] + red[2][lane] + red[3][lane];
            (ws + A.offLocal)[h * 64 + lane] = (nloc > 0) ? tot / S : 0.f;
        }
    } else {
        // ---- direct small-node tile (C<=8), reads v, no K1 dependency ----
        int t = b - A.bbK1 - NUM_HEADS;
        int d = t >> 4, h = t & 15;
        attn_tile(v + (long)A.aD[d] * ROW + h * 64, A.CD[d], 1.0f / (float)A.CD[d],
                  A.KD[d], A.depD[d], h, q, W, temp,
                  ws + A.offNodeOut + (long)A.idxD[d] * ROW + h * 64,
                  fh, qs, qds, sv, ps, red);
    }
}

// ---------------------------------------------------------------------------
// KB: big-node tiles reduce partial slices + attention; last finishing block
// (device-scope counter, zeroed by KA) does the final combine.
// ---------------------------------------------------------------------------
struct KBArgs {
    int nPart, nNodes, nTiles;
    int offLocal, offCnt, offNodeOut;
    int C1[MAXN], CB1[MAXN], off1[MAXN], dep1[MAXN], idx1[MAXN];
};

__global__ __launch_bounds__(256, 4) void kB(const float* __restrict__ q,
                                             const float* __restrict__ W,
                                             const float* __restrict__ temp,
                                             float* __restrict__ ws,
                                             float* __restrict__ out, KBArgs B) {
    __shared__ float fh[64][64];
    __shared__ float qs[64], qds[64], sv[64], ps[64];
    __shared__ float red[4][64];
    __shared__ unsigned lastflag;

    int t = blockIdx.x, tid = threadIdx.x;
    int p = t >> 4, h = t & 15;
    float* node_out = ws + B.offNodeOut;

    attn_tile(ws + (long)B.off1[p] + h * 64, B.CB1[p], 1.0f / (float)B.C1[p],
              64, B.dep1[p], h, q, W, temp,
              node_out + (long)B.idx1[p] * ROW + h * 64,
              fh, qs, qds, sv, ps, red);

    __syncthreads();                       // drain wave-0 stores (vmcnt 0 at barrier)
    if (tid == 0) {
        __threadfence();                   // release: make node_out device-visible
        unsigned old = atomicAdd((unsigned*)(ws + B.offCnt), 1u);
        lastflag = (old == (unsigned)(B.nTiles - 1)) ? 1u : 0u;
    }
    __syncthreads();
    if (lastflag) {
        __threadfence();                   // acquire side
        const float* local_out = ws + B.offLocal;
        float invN = 1.0f / (float)B.nNodes;
        for (int i = tid; i < ROW; i += 256) {
            float tr = 0.f;
            for (int n = 0; n < B.nNodes; ++n) tr += node_out[(long)n * ROW + i];
            out[i] = local_out[i] + tr * invN;
        }
    }
}

// Fallback combine (only used when no big nodes exist, e.g. tiny pos)
__global__ __launch_bounds__(256) void k3_combine(const float* __restrict__ node_out,
                                                  const float* __restrict__ local_out,
                                                  int nNodes,
                                                  float* __restrict__ out) {
    int i = blockIdx.x * 256 + threadIdx.x;
    float tr = 0.f;
    for (int n = 0; n < nNodes; ++n) tr += node_out[(long)n * ROW + i];
    if (nNodes > 0) tr /= (float)nNodes;
    out[i] = local_out[i] + tr;
}

static int floor_log2_host(unsigned x) { int r = 0; while (x >>= 1) ++r; return r; }

extern "C" void kernel_launch(void* const* d_in, const int* in_sizes, int n_in,
                              void* d_out, int out_size, void* d_ws, size_t ws_size,
                              hipStream_t stream) {
    const float* v    = (const float*)d_in[0];
    const float* q    = (const float*)d_in[1];
    const float* W    = (const float*)d_in[2];
    const float* temp = (const float*)d_in[3];
    float* out        = (float*)d_out;
    float* ws         = (float*)d_ws;

    int pos = in_sizes[0] / ROW;

    int n_nodes = 0;
    int nv[MAXN], nd[MAXN];
    if (pos > 0) {
        long l = LEAF_START;
        long r = LEAF_START + (pos < MAX_LEN_TOK ? pos : MAX_LEN_TOK);
        while (l < r) {
            if (l & 1) { nv[n_nodes] = (int)l; nd[n_nodes] = LOG_N - floor_log2_host((unsigned)l); ++n_nodes; ++l; }
            if (r & 1) { --r; nv[n_nodes] = (int)r; nd[n_nodes] = LOG_N - floor_log2_host((unsigned)r); ++n_nodes; }
            l >>= 1; r >>= 1;
        }
    }

    // cpb: smallest in {32,...} whose partial slices fit ws.
    // ws layout: partials | node_out [n_nodes*ROW] | local_out [ROW] | counter
    int cpb_choice = 1024;
    for (int cand : {32, 64, 128, 256, 512, 1024}) {
        long tot_cb = 0;
        for (int i = 0; i < n_nodes; ++i) {
            int L = 1 << nd[i];
            int C = (L > KMAXN) ? L / KMAXN : 1;
            if (C > 8) tot_cb += (C + cand - 1) / cand;
        }
        long need = (tot_cb * (long)SLICE + (long)n_nodes * ROW + ROW + 64) * 4;
        if (need <= (long)ws_size) { cpb_choice = cand; break; }
    }

    KAArgs A{}; KBArgs B{};
    A.pos = pos;
    B.nNodes = n_nodes;
    int off = 0, bb = 0, nPart = 0, nDirect = 0;
    for (int i = 0; i < n_nodes; ++i) {
        int depth = nd[i];
        int L = 1 << depth;
        int a = (nv[i] << depth) - LEAF_START;
        int K = (L < KMAXN) ? L : KMAXN;
        int C = (L > KMAXN) ? L / KMAXN : 1;
        if (C > 8) {
            int CB  = (C + cpb_choice - 1) / cpb_choice;
            int cpb = (C + CB - 1) / CB;
            A.a1[nPart] = a; A.cpb1[nPart] = cpb; A.C1[nPart] = C;
            A.off1[nPart] = off; A.bbase[nPart] = bb;
            B.C1[nPart] = C; B.CB1[nPart] = CB; B.off1[nPart] = off;
            B.dep1[nPart] = depth; B.idx1[nPart] = i;
            off += CB * SLICE;
            bb  += 16 * CB;            // K=64 -> 16 k-groups per cb, cb-major
            ++nPart;
        } else {
            A.aD[nDirect] = a; A.CD[nDirect] = C; A.KD[nDirect] = K;
            A.depD[nDirect] = depth; A.idxD[nDirect] = i;
            ++nDirect;
        }
    }
    A.nPart = nPart; A.bbK1 = bb; A.nDirect = nDirect;
    B.nPart = nPart; B.nTiles = nPart * NUM_HEADS;
    A.offNodeOut = off;
    A.offLocal   = off + n_nodes * ROW;
    A.offCnt     = A.offLocal + ROW;
    B.offNodeOut = A.offNodeOut; B.offLocal = A.offLocal; B.offCnt = A.offCnt;

    int gridA = bb + NUM_HEADS + nDirect * NUM_HEADS;
    hipLaunchKernelGGL(kA, dim3(gridA), dim3(256), 0, stream, v, q, W, temp, ws, A);

    if (nPart > 0) {
        hipLaunchKernelGGL(kB, dim3(B.nTiles), dim3(256), 0, stream,
                           q, W, temp, ws, out, B);
    } else {
        hipLaunchKernelGGL(k3_combine, dim3(4), dim3(256), 0, stream,
                           ws + (long)A.offNodeOut, ws + (long)A.offLocal, n_nodes, out);
    }
}